// Round 1
// baseline (861.955 us; speedup 1.0000x reference)
//
#include <hip/hip_runtime.h>

#define TT    512
#define HH    64
#define NB    4
#define NBLK  256
#define HP    72    // h^T pitch in f16

typedef _Float16 f16x8 __attribute__((ext_vector_type(8)));
typedef _Float16 f16x4 __attribute__((ext_vector_type(4)));
typedef float    f32x4 __attribute__((ext_vector_type(4)));

__device__ __forceinline__ float sigmoidf_(float x) {
    return 1.0f / (1.0f + __expf(-x));
}
__device__ __forceinline__ float tanhf_(float x) {
    return 1.0f - 2.0f / (1.0f + __expf(2.0f * x));
}

// 256 blocks x 512 threads (8 waves). Block owns 4 batches (cols 0..3 of the
// 16-col MFMA tile). Group A = waves 0-3 (layer 1), group C = waves 4-7
// (layer 2, fused K=128 matvec over [h1; h2]).
//
// r10 change: GATE-INTERLEAVED weight rows kill the cell-transpose LDS
// round trip. New global row order: row 64w + 16*tile + 4q + r  <->
// (unit = 16w + 4q + tile, gate = r). After the MFMAs, lane (quad, n)
// holds all 4 gates of 4 complete cells in acc[tile][0..3] — pointwise is
// done in-register by the 16 valid-batch lanes (4 cells each), and the
// h-write packs 4 consecutive units into one ds_write_b64. Row permutation
// changes no summation order -> layer-1 bitwise identical to r9.
// Group C: 4-deep MFMA chain split into two 2-deep partial sums (+1 fp32
// add) to cut 2 MFMA latencies off the critical (longer) C path.
// Precision: f16 weights/h-hop, fp32 accum/bias/pointwise/c (r7: 3.9e-3).
// NOTE (r8 lesson): per-tick producer/consumer across blocks = 4x regression
// (agent-scope acquire invalidates the XCD L2). Handoff stays in-block.
__global__ __launch_bounds__(512) void lstm_mfma(
    const float* __restrict__ x,
    const float* __restrict__ w_ih0, const float* __restrict__ w_hh0,
    const float* __restrict__ b_ih0, const float* __restrict__ b_hh0,
    const float* __restrict__ w_ih1, const float* __restrict__ w_hh1,
    const float* __restrict__ b_ih1, const float* __restrict__ b_hh1,
    const float* __restrict__ w_out, const float* __restrict__ b_out,
    float* __restrict__ out)
{
    __shared__ __align__(16) _Float16 h1T[2][16 * HP];  // h1^T [batch][unit] f16
    __shared__ __align__(16) _Float16 h2T[2][16 * HP];  // h2^T
    __shared__ float xs[TT * 12];                       // x [t][d][4] fp32
    __shared__ __align__(16) float h2f[16 * 68];        // final h2 fp32
    __shared__ float lg[NB][4];

    const int tid   = threadIdx.x;
    const int group = tid >> 8;          // 0 = A (layer 1), 1 = C (layer 2)
    const int w     = (tid >> 6) & 3;    // wave-in-group
    const int lane  = tid & 63;
    const int quad  = lane >> 4;
    const int n     = lane & 15;         // MFMA column = batch slot
    const int b0    = blockIdx.x * NB;

    // ---- persistent weight fragments (gate-interleaved row order) ----
    // In-tile row m of tile b_:  global new-row 64w+16b_+m  <->
    //   unit = 16w + 4*(m>>2) + b_ , gate = m&3 ; original row = 64*gate + unit.
    // A-operand row index for this lane = n; C/D row = 4*quad + r.
    f16x8 whh[4][2], wih[4][2], axf[4];
    f32x4 biasf[4];
    #pragma unroll
    for (int b_ = 0; b_ < 4; ++b_) {
        const int ua   = 16 * w + 4 * (n >> 2) + b_;   // unit of this A-row
        const int orow = 64 * (n & 3) + ua;            // original (gate-major) row
        const float* ph = (group == 0) ? (w_hh0 + orow * HH) : (w_hh1 + orow * HH);
        const float* pi = w_ih1 + orow * HH;
        #pragma unroll
        for (int k0 = 0; k0 < 2; ++k0) {
            #pragma unroll
            for (int j = 0; j < 8; ++j) {
                whh[b_][k0][j] = (_Float16)ph[quad * 8 + 32 * k0 + j];
                wih[b_][k0][j] = (group == 1) ? (_Float16)pi[quad * 8 + 32 * k0 + j]
                                              : (_Float16)0.f;
            }
        }
        const int uc = 16 * w + 4 * quad + b_;         // unit of this C/D row group
        #pragma unroll
        for (int r = 0; r < 4; ++r) {                  // r = gate index (i,f,g,o)
            biasf[b_][r] = (group == 0) ? (b_ih0[64 * r + uc] + b_hh0[64 * r + uc])
                                        : (b_ih1[64 * r + uc] + b_hh1[64 * r + uc]);
        }
        f16x8 ax;
        #pragma unroll
        for (int j = 0; j < 8; ++j) ax[j] = (_Float16)0.f;
        if (group == 0 && quad == 0) {                 // K=3 x-transform
            ax[0] = (_Float16)w_ih0[orow * 3 + 0];
            ax[1] = (_Float16)w_ih0[orow * 3 + 1];
            ax[2] = (_Float16)w_ih0[orow * 3 + 2];
        }
        axf[b_] = ax;
    }

    // ---- LDS init ----
    for (int i = tid; i < 1152; i += 512) {
        ((int*)h1T)[i] = 0;
        ((int*)h2T)[i] = 0;
    }
    for (int i = tid; i < TT * 12; i += 512) {
        const int t = i / 12, rem = i - t * 12;
        const int d = rem >> 2, b = rem & 3;
        xs[i] = x[(size_t)(b0 + b) * (TT * 3) + t * 3 + d];
    }
    __syncthreads();

    // c state: 4 cells per lane (units 16w+4q+{0..3}, batch n) — valid for n<4
    float cr[4] = {0.f, 0.f, 0.f, 0.f};

    for (int t = 0; t <= TT; ++t) {
        if (group == 0) {
            if (t < TT) {
                f16x8 bx;
                #pragma unroll
                for (int j = 0; j < 8; ++j) bx[j] = (_Float16)0.f;
                if (quad == 0) {
                    const float* xp = xs + t * 12 + (lane & 3);
                    bx[0] = (_Float16)xp[0];
                    bx[1] = (_Float16)xp[4];
                    bx[2] = (_Float16)xp[8];
                }
                const _Float16* hsrc = h1T[(t + 1) & 1];
                const f16x8 bh0 = *(const f16x8*)(hsrc + n * HP + quad * 8);
                const f16x8 bh1 = *(const f16x8*)(hsrc + n * HP + quad * 8 + 32);
                f32x4 acc[4];
                #pragma unroll
                for (int b_ = 0; b_ < 4; ++b_) {
                    f32x4 a = __builtin_amdgcn_mfma_f32_16x16x32_f16(axf[b_], bx, biasf[b_], 0, 0, 0);
                    a = __builtin_amdgcn_mfma_f32_16x16x32_f16(whh[b_][0], bh0, a, 0, 0, 0);
                    a = __builtin_amdgcn_mfma_f32_16x16x32_f16(whh[b_][1], bh1, a, 0, 0, 0);
                    acc[b_] = a;
                }
                if (n < 4) {
                    f16x4 hv;
                    #pragma unroll
                    for (int b_ = 0; b_ < 4; ++b_) {
                        const float is = sigmoidf_(acc[b_][0]);
                        const float fs = sigmoidf_(acc[b_][1]);
                        const float gt = tanhf_(acc[b_][2]);
                        const float os = sigmoidf_(acc[b_][3]);
                        cr[b_] = fs * cr[b_] + is * gt;
                        hv[b_] = (_Float16)(os * tanhf_(cr[b_]));
                    }
                    *(f16x4*)(h1T[t & 1] + n * HP + 16 * w + 4 * quad) = hv;
                }
            }
        } else {
            if (t >= 1) {
                // fused K=128 matvec over [h1(t-1); h2(t-2)], split into two
                // 2-deep partial chains to shorten the critical path
                const _Float16* h1src = h1T[(t + 1) & 1];
                const _Float16* h2src = h2T[(t + 1) & 1];
                const f16x8 b10 = *(const f16x8*)(h1src + n * HP + quad * 8);
                const f16x8 b11 = *(const f16x8*)(h1src + n * HP + quad * 8 + 32);
                const f16x8 b20 = *(const f16x8*)(h2src + n * HP + quad * 8);
                const f16x8 b21 = *(const f16x8*)(h2src + n * HP + quad * 8 + 32);
                const f32x4 zero = {0.f, 0.f, 0.f, 0.f};
                f32x4 acc[4];
                #pragma unroll
                for (int b_ = 0; b_ < 4; ++b_) {
                    f32x4 p = __builtin_amdgcn_mfma_f32_16x16x32_f16(wih[b_][0], b10, biasf[b_], 0, 0, 0);
                    p = __builtin_amdgcn_mfma_f32_16x16x32_f16(wih[b_][1], b11, p, 0, 0, 0);
                    f32x4 q4 = __builtin_amdgcn_mfma_f32_16x16x32_f16(whh[b_][0], b20, zero, 0, 0, 0);
                    q4 = __builtin_amdgcn_mfma_f32_16x16x32_f16(whh[b_][1], b21, q4, 0, 0, 0);
                    acc[b_] = p + q4;
                }
                if (n < 4) {
                    f16x4 hv;
                    f32x4 hf;
                    #pragma unroll
                    for (int b_ = 0; b_ < 4; ++b_) {
                        const float is = sigmoidf_(acc[b_][0]);
                        const float fs = sigmoidf_(acc[b_][1]);
                        const float gt = tanhf_(acc[b_][2]);
                        const float os = sigmoidf_(acc[b_][3]);
                        cr[b_] = fs * cr[b_] + is * gt;
                        const float h = os * tanhf_(cr[b_]);
                        hv[b_] = (_Float16)h;
                        hf[b_] = h;
                    }
                    *(f16x4*)(h2T[t & 1] + n * HP + 16 * w + 4 * quad) = hv;   // h2(t-1)
                    if (t == TT)
                        *(f32x4*)(h2f + n * 68 + 16 * w + 4 * quad) = hf;      // h2(TT-1) fp32
                }
            }
        }
        __syncthreads();
    }

    // ---- epilogue: logits + softmax on fp32 h2 ----
    if (tid < 16) {
        const int b = tid & 3, o = tid >> 2;
        float acc = b_out[o];
        #pragma unroll
        for (int j = 0; j < HH; ++j)
            acc = fmaf(w_out[o * HH + j], h2f[b * 68 + j], acc);
        lg[b][o] = acc;
    }
    __syncthreads();
    if (tid < NB) {
        const int b = tid;
        const float l0 = lg[b][0], l1 = lg[b][1], l2 = lg[b][2], l3 = lg[b][3];
        const float m  = fmaxf(fmaxf(l0, l1), fmaxf(l2, l3));
        const float e0 = __expf(l0 - m), e1 = __expf(l1 - m);
        const float e2 = __expf(l2 - m), e3 = __expf(l3 - m);
        const float sum = 1.0f / (e0 + e1 + e2 + e3);
        out[(b0 + b) * 4 + 0] = e0 * sum;
        out[(b0 + b) * 4 + 1] = e1 * sum;
        out[(b0 + b) * 4 + 2] = e2 * sum;
        out[(b0 + b) * 4 + 3] = e3 * sum;
    }
}

extern "C" void kernel_launch(void* const* d_in, const int* in_sizes, int n_in,
                              void* d_out, int out_size, void* d_ws, size_t ws_size,
                              hipStream_t stream) {
    const float* x     = (const float*)d_in[0];
    const float* w_ih0 = (const float*)d_in[1];
    const float* w_hh0 = (const float*)d_in[2];
    const float* b_ih0 = (const float*)d_in[3];
    const float* b_hh0 = (const float*)d_in[4];
    const float* w_ih1 = (const float*)d_in[5];
    const float* w_hh1 = (const float*)d_in[6];
    const float* b_ih1 = (const float*)d_in[7];
    const float* b_hh1 = (const float*)d_in[8];
    const float* w_out = (const float*)d_in[9];
    const float* b_out = (const float*)d_in[10];
    float* out = (float*)d_out;

    hipLaunchKernelGGL(lstm_mfma, dim3(NBLK), dim3(512), 0, stream,
                       x, w_ih0, w_hh0, b_ih0, b_hh0,
                       w_ih1, w_hh1, b_ih1, b_hh1,
                       w_out, b_out, out);
}